// Round 17
// baseline (462.762 us; speedup 1.0000x reference)
//
#include <hip/hip_runtime.h>

// Problem constants
constexpr int Bc   = 16;
constexpr int Cc   = 64;
constexpr int Fc   = 128;
constexpr int TPc  = 100;
constexpr int Gc   = Bc * TPc;      // 1600 graphs
constexpr int Nc   = Gc * Cc;       // 102400 nodes
constexpr int Ec   = 576;
constexpr int NHID = 128;
constexpr int NOUTc= 64;
constexpr int Kc   = 58;            // ceil(0.9*64)
constexpr int Nkc  = Gc * Kc;       // 92800

// ---------------- K0: build dense per-graph aggregation matrices ----------------
__global__ void k0_prep(const int* __restrict__ ei, const float* __restrict__ ew,
                        float* __restrict__ A1, float* __restrict__ AP,
                        double* bn1S, double* bn1Q, double* bn2S, double* bn2Q) {
    __shared__ float deg1[64], degP[64], dis1[64], disP[64];
    __shared__ float A1L[4096], APL[4096];
    int t = threadIdx.x;
    if (t < 64) { deg1[t] = 1.0f; degP[t] = 1.0f; }       // self-loop weight 1
    for (int i = t; i < 4096; i += 256) { A1L[i] = 0.f; APL[i] = 0.f; }
    if (t < 128) { bn1S[t] = 0.0; bn1Q[t] = 0.0; }
    if (t < 64)  { bn2S[t] = 0.0; bn2Q[t] = 0.0; }
    __syncthreads();
    for (int e = t; e < Ec; e += 256) {
        int c = ei[Ec + e];
        atomicAdd(&deg1[c], ew[e]);
        atomicAdd(&degP[c], 1.0f);
    }
    __syncthreads();
    if (t < 64) { dis1[t] = 1.0f / sqrtf(deg1[t]); disP[t] = 1.0f / sqrtf(degP[t]); }
    __syncthreads();
    for (int e = t; e < Ec; e += 256) {
        int r = ei[e], c = ei[Ec + e];
        atomicAdd(&A1L[c * 64 + r], dis1[r] * ew[e] * dis1[c]);
        atomicAdd(&APL[c * 64 + r], disP[r] * disP[c]);
    }
    __syncthreads();
    if (t < 64) {
        A1L[t * 65] += dis1[t] * dis1[t];
        APL[t * 65] += disP[t] * disP[t];
    }
    __syncthreads();
    for (int i = t; i < 4096; i += 256) { A1[i] = A1L[i]; AP[i] = APL[i]; }
}

// ---------------- K_trans: h[b][c][f][tp] -> XT[g=b*100+tp][f][c] ----------------
__global__ __launch_bounds__(256)
void k_trans(const float* __restrict__ h, float* __restrict__ XT) {
    __shared__ float tile[64 * 101];   // [c][tp]
    int blk = blockIdx.x;              // 0..2047
    int b = blk >> 7, f = blk & 127;
    int t = threadIdx.x;
    const float* hb = h + (size_t)b * 819200 + (size_t)f * 100;
    for (int i = t; i < 6400; i += 256) {
        unsigned c = (unsigned)i / 100u;
        unsigned tp = (unsigned)i - c * 100u;
        tile[c * 101 + tp] = hb[(size_t)c * 12800 + tp];
    }
    __syncthreads();
    float* xb = XT + (size_t)b * 100 * 8192 + f * 64;
    for (int j = t; j < 6400; j += 256) {
        int tp = j >> 6, c = j & 63;
        xb[(size_t)tp * 8192 + c] = tile[c * 101 + tp];
    }
}

// ---------------- K1: per-graph gc1 = A1*(X*W1)+b1, BN1 partial sums ----------------
// R16: same quarter-tile algorithm as the measured-good R12 version, but 512-thread
// blocks with a HALVED per-thread tile (4x4, acc=16 VGPR): doubles resident waves
// (4 blocks x 8 waves = 32/CU) without touching the 64-VGPR wall that killed the
// work-per-thread variants (R9/R11/R13/R15). LDS 32KB unchanged.
__global__ __launch_bounds__(512, 8)
void k1_gc1(const float* __restrict__ XT, const float* __restrict__ W1,
            const float* __restrict__ b1, const float* __restrict__ A1,
            float* __restrict__ Y1, double* bn1S, double* bn1Q) {
    __shared__ float Xh[8192];    // phase A: X quarter [0..2047] + W1 quarter [2048..6143]
                                  // phase B: H [c=64][f=128] (full 32KB); then BN reduction
    int g = blockIdx.x;
    int t = threadIdx.x;          // 0..511
    int tx = t & 31, ty = t >> 5; // ty 0..15: rows ty*4..ty*4+3 ; tx: cols tx*4..tx*4+3

    float acc[4][4];
#pragma unroll
    for (int i = 0; i < 4; ++i)
#pragma unroll
        for (int j = 0; j < 4; ++j) acc[i][j] = 0.f;

    for (int kq = 0; kq < 4; ++kq) {
        __syncthreads();  // protects stage buffers across kq iterations
        {   // X quarter: 512 float4, one per thread
            const float4* xsrc = (const float4*)(XT + (size_t)g * 8192 + kq * 2048);
            ((float4*)Xh)[t] = xsrc[t];
            // W1 quarter: 1024 float4, two per thread
            const float4* wsrc = (const float4*)(W1 + kq * 4096);
            float4* wdst = (float4*)(Xh + 2048);
            wdst[t]       = wsrc[t];
            wdst[512 + t] = wsrc[512 + t];
        }
        __syncthreads();
        for (int kk = 0; kk < 32; ++kk) {
            float4 x4 = *(const float4*)&Xh[kk * 64 + ty * 4];
            float4 w  = *(const float4*)&Xh[2048 + kk * 128 + tx * 4];
            float xr[4] = {x4.x, x4.y, x4.z, x4.w};
#pragma unroll
            for (int i = 0; i < 4; ++i) {
                acc[i][0] += xr[i] * w.x;
                acc[i][1] += xr[i] * w.y;
                acc[i][2] += xr[i] * w.z;
                acc[i][3] += xr[i] * w.w;
            }
        }
    }
    __syncthreads();   // all stage-buffer reads done
    // H -> Xh (full 32KB), layout [c][f] stride 128
#pragma unroll
    for (int i = 0; i < 4; ++i) {
        float4 v = make_float4(acc[i][0], acc[i][1], acc[i][2], acc[i][3]);
        *(float4*)&Xh[(ty * 4 + i) * 128 + tx * 4] = v;
    }
    __syncthreads();
    // GEMM2: Y = A1 * H + b1  (A1 from global: ty-uniform float4, L1-resident)
    float acy[4][4];
    float4 bb = *(const float4*)&b1[tx * 4];
#pragma unroll
    for (int i = 0; i < 4; ++i) { acy[i][0] = bb.x; acy[i][1] = bb.y; acy[i][2] = bb.z; acy[i][3] = bb.w; }
    for (int rr = 0; rr < 16; ++rr) {
        float4 hrow[4];
#pragma unroll
        for (int q = 0; q < 4; ++q) hrow[q] = *(const float4*)&Xh[(rr * 4 + q) * 128 + tx * 4];
#pragma unroll
        for (int i = 0; i < 4; ++i) {
            float4 a4 = *(const float4*)&A1[(ty * 4 + i) * 64 + rr * 4];
            acy[i][0] += a4.x * hrow[0].x + a4.y * hrow[1].x + a4.z * hrow[2].x + a4.w * hrow[3].x;
            acy[i][1] += a4.x * hrow[0].y + a4.y * hrow[1].y + a4.z * hrow[2].y + a4.w * hrow[3].y;
            acy[i][2] += a4.x * hrow[0].z + a4.y * hrow[1].z + a4.z * hrow[2].z + a4.w * hrow[3].z;
            acy[i][3] += a4.x * hrow[0].w + a4.y * hrow[1].w + a4.z * hrow[2].w + a4.w * hrow[3].w;
        }
    }
    // store + BN partials
    float ps[4] = {0, 0, 0, 0}, pq[4] = {0, 0, 0, 0};
    float* Yg = Y1 + (size_t)g * 64 * 128;
#pragma unroll
    for (int i = 0; i < 4; ++i) {
        float4 v = make_float4(acy[i][0], acy[i][1], acy[i][2], acy[i][3]);
        *(float4*)&Yg[(ty * 4 + i) * 128 + tx * 4] = v;
#pragma unroll
        for (int j = 0; j < 4; ++j) { ps[j] += acy[i][j]; pq[j] += acy[i][j] * acy[i][j]; }
    }
    __syncthreads();   // all H reads done before reuse as reduction area
    float* redS = Xh;            // 16 x 128
    float* redQ = Xh + 2048;
#pragma unroll
    for (int j = 0; j < 4; ++j) {
        redS[ty * 128 + tx * 4 + j] = ps[j];
        redQ[ty * 128 + tx * 4 + j] = pq[j];
    }
    __syncthreads();
    if (t < 128) {
        float S = 0.f, Q = 0.f;
        for (int y = 0; y < 16; ++y) { S += redS[y * 128 + t]; Q += redQ[y * 128 + t]; }
        atomicAdd(&bn1S[t], (double)S);
        atomicAdd(&bn1Q[t], (double)Q);
    }
}

// ---------------- BN finalize (shared by bn1/bn2) ----------------
__global__ void k_bnfin(const double* __restrict__ S, const double* __restrict__ Q,
                        const float* __restrict__ gam, const float* __restrict__ bet,
                        float* __restrict__ scale, float* __restrict__ shift, double invN) {
    int t = threadIdx.x;
    double m = S[t] * invN;
    double v = Q[t] * invN - m * m;
    double rstd = 1.0 / sqrt(v + 1e-5);
    float sc = (float)((double)gam[t] * rstd);
    scale[t] = sc;
    shift[t] = bet[t] - (float)m * sc;
}

// ---------------- K3a: BN1+PReLU, pooling score, top-k, H2 = (s*Xkept)@W2 ----------------
// (R14/R16 measured-good version, untouched.)
__global__ __launch_bounds__(256, 2)
void k3a_pool(float* __restrict__ Y1, const float* __restrict__ scale1,
              const float* __restrict__ shift1, const float* __restrict__ a1,
              const float* __restrict__ Wp, const float* __restrict__ bp,
              const float* __restrict__ AP, const float* __restrict__ W2) {
    __shared__ float Xs[64 * 132];      // x rows, stride 132
    __shared__ float slin[64], psum[256], score[64];
    __shared__ int   rnk[64], ord[64];
    int g = blockIdx.x, t = threadIdx.x;
    int tx = t & 31, ty = t >> 5;
    float alpha1 = a1[0];

    float* slab = Y1 + (size_t)g * 8192;
    {   // float4 staging: f4 = t&31 is fixed per thread -> scale/shift loaded once
        const float4* Yg4 = (const float4*)slab;
        float4 sc4 = *(const float4*)&scale1[tx * 4];
        float4 sh4 = *(const float4*)&shift1[tx * 4];
#pragma unroll
        for (int it = 0; it < 8; ++it) {
            int e4 = it * 256 + t;       // float4 index, 32 per row
            int c = e4 >> 5;
            float4 v = Yg4[e4];
            v.x = v.x * sc4.x + sh4.x; v.x = (v.x >= 0.f) ? v.x : alpha1 * v.x;
            v.y = v.y * sc4.y + sh4.y; v.y = (v.y >= 0.f) ? v.y : alpha1 * v.y;
            v.z = v.z * sc4.z + sh4.z; v.z = (v.z >= 0.f) ? v.z : alpha1 * v.z;
            v.w = v.w * sc4.w + sh4.w; v.w = (v.w >= 0.f) ? v.w : alpha1 * v.w;
            *(float4*)&Xs[c * 132 + tx * 4] = v;
        }
    }
    __syncthreads();
    // pooling: slin = X @ Wp  (4 threads per row)
    {
        int rr = t >> 2, q4 = t & 3;
        float sp = 0.f;
        for (int m = 0; m < 32; ++m) sp += Xs[rr * 132 + q4 * 32 + m] * Wp[q4 * 32 + m];
        psum[t] = sp;
    }
    __syncthreads();
    if (t < 64) slin[t] = psum[t * 4] + psum[t * 4 + 1] + psum[t * 4 + 2] + psum[t * 4 + 3];
    __syncthreads();
    // score matvec, parallel over 256 threads: node n = t>>2, quarter q = t&3
    {
        int n = t >> 2, q = t & 3;
        float acc = 0.f;
#pragma unroll
        for (int m = 0; m < 16; ++m) acc += AP[n * 64 + q * 16 + m] * slin[q * 16 + m];
        psum[t] = acc;
    }
    __syncthreads();
    if (t < 64) score[t] = tanhf(bp[0] + psum[t * 4] + psum[t * 4 + 1] + psum[t * 4 + 2] + psum[t * 4 + 3]);
    __syncthreads();
    // rank, parallel over 256 threads: node n = t>>2 counts c2 in its 16-chunk
    {
        int n = t >> 2, q = t & 3;
        float sc = score[n];
        int cnt = 0;
#pragma unroll
        for (int m = 0; m < 16; ++m) {
            int c2 = q * 16 + m;
            float o = score[c2];
            cnt += (o > sc) || (o == sc && c2 < n);  // stable descending rank (top_k tie rule)
        }
        psum[t] = (float)cnt;
    }
    __syncthreads();
    if (t < 64) {
        int cnt = (int)(psum[t * 4] + psum[t * 4 + 1] + psum[t * 4 + 2] + psum[t * 4 + 3]);
        rnk[t] = cnt;
        if (cnt < Kc) ord[cnt] = t;
        ((int*)(slab + 4096))[t] = cnt;              // rnk -> global slab
    }
    __syncthreads();

    // H2[r][o] = score[ord[r]] * sum_k Xs[ord[r]][k] * W2[k][o]   (rows >= Kc are zero)
    {
        int row0 = ty * 8;
        float acc2[8][2];
        int   cidx[8];
        float srow[8];
#pragma unroll
        for (int i = 0; i < 8; ++i) {
            acc2[i][0] = 0.f; acc2[i][1] = 0.f;
            int r = row0 + i;
            if (r < Kc) { cidx[i] = ord[r]; srow[i] = score[cidx[i]]; }
            else        { cidx[i] = 0;      srow[i] = 0.f; }
        }
        for (int k0 = 0; k0 < 128; k0 += 4) {
            float4 xv[8];
#pragma unroll
            for (int i = 0; i < 8; ++i) xv[i] = *(const float4*)&Xs[cidx[i] * 132 + k0];
#pragma unroll
            for (int q = 0; q < 4; ++q) {
                float2 w = *(const float2*)&W2[(k0 + q) * 64 + tx * 2];
#pragma unroll
                for (int i = 0; i < 8; ++i) {
                    float xq = (q == 0) ? xv[i].x : (q == 1) ? xv[i].y : (q == 2) ? xv[i].z : xv[i].w;
                    acc2[i][0] += xq * w.x;
                    acc2[i][1] += xq * w.y;
                }
            }
        }
        // write H2 to the global slab (coalesced float2; rows >= Kc get zeros)
#pragma unroll
        for (int i = 0; i < 8; ++i) {
            *(float2*)&slab[(row0 + i) * 64 + tx * 2] =
                make_float2(acc2[i][0] * srow[i], acc2[i][1] * srow[i]);
        }
    }
}

// ---------------- K3b: build A2, Y2 = A2@H2 + b2, BN2 partials ----------------
// (Measured-good R7 version, untouched.)
__global__ __launch_bounds__(256, 2)
void k3b_gc2(const float* __restrict__ Y1, const int* __restrict__ ei,
             const float* __restrict__ ew, const float* __restrict__ b2,
             float* __restrict__ Y2, double* bn2S, double* bn2Q) {
    __shared__ float H2s[64 * 68];      // stride 68 (16B-aligned rows)
    __shared__ float A2s[4096];
    __shared__ float dis2[64], deg2[64];
    __shared__ int   rnk[64];
    int g = blockIdx.x, t = threadIdx.x;
    int tx = t & 31, ty = t >> 5;

    const float* slab = Y1 + (size_t)g * 8192;
    {   // stage H2 (coalesced float4 reads, 64 rows x 64)
        const float4* src = (const float4*)slab;
#pragma unroll
        for (int it = 0; it < 4; ++it) {
            int i4 = it * 256 + t;
            int r = i4 >> 4, c4 = i4 & 15;
            *(float4*)&H2s[r * 68 + c4 * 4] = src[i4];
        }
    }
    if (t < 64) rnk[t] = ((const int*)(slab + 4096))[t];
    {
        float4 z = make_float4(0.f, 0.f, 0.f, 0.f);
        float4* A2s4 = (float4*)A2s;
#pragma unroll
        for (int j = 0; j < 4; ++j) A2s4[j * 256 + t] = z;
    }
    if (t < 64) deg2[t] = 1.0f;        // self-loop
    __syncthreads();
    for (int e = t; e < Ec; e += 256) {
        int r = ei[e], c = ei[Ec + e];
        if (rnk[r] < Kc && rnk[c] < Kc) atomicAdd(&deg2[rnk[c]], ew[e]);
    }
    __syncthreads();
    if (t < 64) dis2[t] = 1.0f / sqrtf(deg2[t]);
    __syncthreads();
    for (int e = t; e < Ec; e += 256) {
        int r = ei[e], c = ei[Ec + e];
        int rkr = rnk[r], rkc = rnk[c];
        if (rkr < Kc && rkc < Kc) atomicAdd(&A2s[rkc * 64 + rkr], dis2[rkr] * ew[e] * dis2[rkc]);
    }
    __syncthreads();
    if (t < Kc) A2s[t * 65] += dis2[t] * dis2[t];
    __syncthreads();

    // Y2 = A2s * H2 + b2
    float acy[8][2];
    float2 b2v = *(const float2*)&b2[tx * 2];
#pragma unroll
    for (int i = 0; i < 8; ++i) { acy[i][0] = b2v.x; acy[i][1] = b2v.y; }
    for (int rr = 0; rr < 16; ++rr) {
        float2 h2[4];
#pragma unroll
        for (int q = 0; q < 4; ++q) h2[q] = *(const float2*)&H2s[(rr * 4 + q) * 68 + tx * 2];
#pragma unroll
        for (int i = 0; i < 8; ++i) {
            float4 a4 = *(const float4*)&A2s[(ty * 8 + i) * 64 + rr * 4];
            acy[i][0] += a4.x * h2[0].x + a4.y * h2[1].x + a4.z * h2[2].x + a4.w * h2[3].x;
            acy[i][1] += a4.x * h2[0].y + a4.y * h2[1].y + a4.z * h2[2].y + a4.w * h2[3].y;
        }
    }
    float s0 = 0.f, s1 = 0.f, q0 = 0.f, q1 = 0.f;
    float* Y2g = Y2 + (size_t)g * Kc * 64;
#pragma unroll
    for (int i = 0; i < 8; ++i) {
        int ck = ty * 8 + i;
        if (ck < Kc) {
            float2 v = make_float2(acy[i][0], acy[i][1]);
            *(float2*)&Y2g[ck * 64 + tx * 2] = v;
            s0 += v.x; s1 += v.y; q0 += v.x * v.x; q1 += v.y * v.y;
        }
    }
    __syncthreads();   // all H2s reads done before reuse as reduction area
    float* redS = H2s;
    float* redQ = H2s + 512;
    redS[ty * 64 + tx * 2]     = s0;
    redS[ty * 64 + tx * 2 + 1] = s1;
    redQ[ty * 64 + tx * 2]     = q0;
    redQ[ty * 64 + tx * 2 + 1] = q1;
    __syncthreads();
    if (t < 64) {
        float S = 0.f, Q = 0.f;
        for (int y = 0; y < 8; ++y) { S += redS[y * 64 + t]; Q += redQ[y * 64 + t]; }
        atomicAdd(&bn2S[t], (double)S);
        atomicAdd(&bn2Q[t], (double)Q);
    }
}

// ---------------- K5: final BN2+PReLU, write x2 and z_seq ----------------
__global__ void k5_out(const float* __restrict__ Y2, const float* __restrict__ scale2,
                       const float* __restrict__ shift2, const float* __restrict__ a2v,
                       float* __restrict__ out) {
    __shared__ float red[4 * 64];
    int g = blockIdx.x, t = threadIdx.x;
    float alpha = a2v[0];
    const float* Yg = Y2 + (size_t)g * Kc * 64;
    float* Og = out + (size_t)g * Kc * 64;
    int c = t & 63, rg = t >> 6;
    float part = 0.f;
    for (int rk = rg; rk < Kc; rk += 4) {
        float v = Yg[rk * 64 + c] * scale2[c] + shift2[c];
        v = (v >= 0.f) ? v : alpha * v;
        Og[rk * 64 + c] = v;
        part += v;
    }
    red[rg * 64 + c] = part;
    __syncthreads();
    if (t < 64) {
        float z = (red[t] + red[64 + t] + red[128 + t] + red[192 + t]) / (float)Kc;
        int b = g / TPc, tp = g % TPc;
        out[(size_t)Nkc * 64 + (size_t)b * NOUTc * TPc + t * TPc + tp] = z;
    }
}

extern "C" void kernel_launch(void* const* d_in, const int* in_sizes, int n_in,
                              void* d_out, int out_size, void* d_ws, size_t ws_size,
                              hipStream_t stream) {
    const float* h   = (const float*)d_in[0];
    const int*   ei  = (const int*)  d_in[1];
    const float* ew  = (const float*)d_in[2];
    const float* W1  = (const float*)d_in[3];
    const float* b1  = (const float*)d_in[4];
    const float* g1  = (const float*)d_in[5];
    const float* be1 = (const float*)d_in[6];
    const float* a1  = (const float*)d_in[7];
    const float* Wp  = (const float*)d_in[8];
    const float* bp  = (const float*)d_in[9];
    const float* W2  = (const float*)d_in[10];
    const float* b2  = (const float*)d_in[11];
    const float* g2  = (const float*)d_in[12];
    const float* be2 = (const float*)d_in[13];
    const float* a2  = (const float*)d_in[14];

    char* ws = (char*)d_ws;
    double* bn1S   = (double*)(ws + 0);
    double* bn1Q   = (double*)(ws + 1024);
    double* bn2S   = (double*)(ws + 2048);
    double* bn2Q   = (double*)(ws + 2560);
    float*  scale1 = (float*)(ws + 3072);
    float*  shift1 = (float*)(ws + 3584);
    float*  scale2 = (float*)(ws + 4096);
    float*  shift2 = (float*)(ws + 4352);
    float*  A1     = (float*)(ws + 4608);
    float*  AP     = (float*)(ws + 20992);
    float*  XT     = (float*)(ws + 37376);                 // [g][f][c] = 52428800 B
    float*  Y1     = XT;                                   // in-place; k3a also writes H2+rnk into slab fronts
    float*  Y2     = (float*)(ws + 37376 + 52428800);      // Nk*64 f32 = 23756800 B
    float*  out    = (float*)d_out;

    hipLaunchKernelGGL(k0_prep, dim3(1), dim3(256), 0, stream,
                       ei, ew, A1, AP, bn1S, bn1Q, bn2S, bn2Q);
    hipLaunchKernelGGL(k_trans, dim3(2048), dim3(256), 0, stream, h, XT);
    hipLaunchKernelGGL(k1_gc1, dim3(Gc), dim3(512), 0, stream,
                       XT, W1, b1, A1, Y1, bn1S, bn1Q);
    hipLaunchKernelGGL(k_bnfin, dim3(1), dim3(128), 0, stream,
                       bn1S, bn1Q, g1, be1, scale1, shift1, 1.0 / (double)Nc);
    hipLaunchKernelGGL(k3a_pool, dim3(Gc), dim3(256), 0, stream,
                       Y1, scale1, shift1, a1, Wp, bp, AP, W2);
    hipLaunchKernelGGL(k3b_gc2, dim3(Gc), dim3(256), 0, stream,
                       Y1, ei, ew, b2, Y2, bn2S, bn2Q);
    hipLaunchKernelGGL(k_bnfin, dim3(1), dim3(64), 0, stream,
                       bn2S, bn2Q, g2, be2, scale2, shift2, 1.0 / (double)Nkc);
    hipLaunchKernelGGL(k5_out, dim3(Gc), dim3(256), 0, stream,
                       Y2, scale2, shift2, a2, out);
}

// Round 18
// 218.853 us; speedup vs baseline: 2.1145x; 2.1145x over previous
//
#include <hip/hip_runtime.h>

// Problem constants
constexpr int Bc   = 16;
constexpr int Cc   = 64;
constexpr int Fc   = 128;
constexpr int TPc  = 100;
constexpr int Gc   = Bc * TPc;      // 1600 graphs
constexpr int Nc   = Gc * Cc;       // 102400 nodes
constexpr int Ec   = 576;
constexpr int NHID = 128;
constexpr int NOUTc= 64;
constexpr int Kc   = 58;            // ceil(0.9*64)
constexpr int Nkc  = Gc * Kc;       // 92800

// ---------------- K0: build dense per-graph aggregation matrices ----------------
__global__ void k0_prep(const int* __restrict__ ei, const float* __restrict__ ew,
                        float* __restrict__ A1, float* __restrict__ AP,
                        double* bn1S, double* bn1Q, double* bn2S, double* bn2Q) {
    __shared__ float deg1[64], degP[64], dis1[64], disP[64];
    __shared__ float A1L[4096], APL[4096];
    int t = threadIdx.x;
    if (t < 64) { deg1[t] = 1.0f; degP[t] = 1.0f; }       // self-loop weight 1
    for (int i = t; i < 4096; i += 256) { A1L[i] = 0.f; APL[i] = 0.f; }
    if (t < 128) { bn1S[t] = 0.0; bn1Q[t] = 0.0; }
    if (t < 64)  { bn2S[t] = 0.0; bn2Q[t] = 0.0; }
    __syncthreads();
    for (int e = t; e < Ec; e += 256) {
        int c = ei[Ec + e];
        atomicAdd(&deg1[c], ew[e]);
        atomicAdd(&degP[c], 1.0f);
    }
    __syncthreads();
    if (t < 64) { dis1[t] = 1.0f / sqrtf(deg1[t]); disP[t] = 1.0f / sqrtf(degP[t]); }
    __syncthreads();
    for (int e = t; e < Ec; e += 256) {
        int r = ei[e], c = ei[Ec + e];
        atomicAdd(&A1L[c * 64 + r], dis1[r] * ew[e] * dis1[c]);
        atomicAdd(&APL[c * 64 + r], disP[r] * disP[c]);
    }
    __syncthreads();
    if (t < 64) {
        A1L[t * 65] += dis1[t] * dis1[t];
        APL[t * 65] += disP[t] * disP[t];
    }
    __syncthreads();
    for (int i = t; i < 4096; i += 256) { A1[i] = A1L[i]; AP[i] = APL[i]; }
}

// ---------------- K_trans: h[b][c][f][tp] -> XT[g=b*100+tp][f][c] ----------------
__global__ __launch_bounds__(256)
void k_trans(const float* __restrict__ h, float* __restrict__ XT) {
    __shared__ float tile[64 * 101];   // [c][tp]
    int blk = blockIdx.x;              // 0..2047
    int b = blk >> 7, f = blk & 127;
    int t = threadIdx.x;
    const float* hb = h + (size_t)b * 819200 + (size_t)f * 100;
    for (int i = t; i < 6400; i += 256) {
        unsigned c = (unsigned)i / 100u;
        unsigned tp = (unsigned)i - c * 100u;
        tile[c * 101 + tp] = hb[(size_t)c * 12800 + tp];
    }
    __syncthreads();
    float* xb = XT + (size_t)b * 100 * 8192 + f * 64;
    for (int j = t; j < 6400; j += 256) {
        int tp = j >> 6, c = j & 63;
        xb[(size_t)tp * 8192 + c] = tile[c * 101 + tp];
    }
}

// ---------------- K1: per-graph gc1 = A1*(X*W1)+b1, BN1 partial sums ----------------
// EXACT R12/R16 measured-good version (80 us, 256 thr, VGPR 64, no spill).
// PLATEAUED -- five variants failed: W1-global (R9, loses L1 broadcast),
// reg-prefetch (R11, spill), 2-graph (R13, VGPR wall), async-DMA dbuf (R15,
// L1 bypass + barrier drain), 512-thr half-tile (R17, 32-VGPR squeeze, 604MB
// scratch). The 64-VGPR / L1-broadcast / barrier-drain constraint triangle
// pins this shape. DO NOT TOUCH.
__global__ __launch_bounds__(256, 4)
void k1_gc1(const float* __restrict__ XT, const float* __restrict__ W1,
            const float* __restrict__ b1, const float* __restrict__ A1,
            float* __restrict__ Y1, double* bn1S, double* bn1Q) {
    __shared__ float Xh[8192];    // phase A: X quarter [0..2047] + W1 quarter [2048..6143]
                                  // phase B: H [c=64][f=128] (full 32KB); then BN reduction
    int g = blockIdx.x;
    int t = threadIdx.x;
    int tx = t & 31, ty = t >> 5;

    float acc[8][4];
#pragma unroll
    for (int i = 0; i < 8; ++i)
#pragma unroll
        for (int j = 0; j < 4; ++j) acc[i][j] = 0.f;

    for (int kq = 0; kq < 4; ++kq) {
        __syncthreads();  // protects stage buffers across kq iterations
        {   // X quarter: XT slab is [k][c] -> quarter kq is a contiguous 8KB run
            const float4* xsrc = (const float4*)(XT + (size_t)g * 8192 + kq * 2048);
            float4* xdst = (float4*)Xh;
            xdst[t]       = xsrc[t];
            xdst[256 + t] = xsrc[256 + t];
            // W1 quarter: rows kq*32..kq*32+31, contiguous 16KB run
            const float4* wsrc = (const float4*)(W1 + kq * 4096);
            float4* wdst = (float4*)(Xh + 2048);
#pragma unroll
            for (int it = 0; it < 4; ++it) wdst[it * 256 + t] = wsrc[it * 256 + t];
        }
        __syncthreads();
        for (int kk = 0; kk < 32; ++kk) {
            float4 x0 = *(const float4*)&Xh[kk * 64 + ty * 8];
            float4 x1 = *(const float4*)&Xh[kk * 64 + ty * 8 + 4];
            float4 w  = *(const float4*)&Xh[2048 + kk * 128 + tx * 4];
            float xr[8] = {x0.x, x0.y, x0.z, x0.w, x1.x, x1.y, x1.z, x1.w};
#pragma unroll
            for (int i = 0; i < 8; ++i) {
                acc[i][0] += xr[i] * w.x;
                acc[i][1] += xr[i] * w.y;
                acc[i][2] += xr[i] * w.z;
                acc[i][3] += xr[i] * w.w;
            }
        }
    }
    __syncthreads();   // all stage-buffer reads done
    // H -> Xh (full 32KB), layout [c][f] stride 128
#pragma unroll
    for (int i = 0; i < 8; ++i) {
        float4 v = make_float4(acc[i][0], acc[i][1], acc[i][2], acc[i][3]);
        *(float4*)&Xh[(ty * 8 + i) * 128 + tx * 4] = v;
    }
    __syncthreads();
    // GEMM2: Y = A1 * H + b1  (A1 from global: ty-uniform float4, L1-resident)
    float acy[8][4];
    float4 bb = *(const float4*)&b1[tx * 4];
#pragma unroll
    for (int i = 0; i < 8; ++i) { acy[i][0] = bb.x; acy[i][1] = bb.y; acy[i][2] = bb.z; acy[i][3] = bb.w; }
    for (int rr = 0; rr < 16; ++rr) {
        float4 hrow[4];
#pragma unroll
        for (int q = 0; q < 4; ++q) hrow[q] = *(const float4*)&Xh[(rr * 4 + q) * 128 + tx * 4];
#pragma unroll
        for (int i = 0; i < 8; ++i) {
            float4 a4 = *(const float4*)&A1[(ty * 8 + i) * 64 + rr * 4];
            acy[i][0] += a4.x * hrow[0].x + a4.y * hrow[1].x + a4.z * hrow[2].x + a4.w * hrow[3].x;
            acy[i][1] += a4.x * hrow[0].y + a4.y * hrow[1].y + a4.z * hrow[2].y + a4.w * hrow[3].y;
            acy[i][2] += a4.x * hrow[0].z + a4.y * hrow[1].z + a4.z * hrow[2].z + a4.w * hrow[3].z;
            acy[i][3] += a4.x * hrow[0].w + a4.y * hrow[1].w + a4.z * hrow[2].w + a4.w * hrow[3].w;
        }
    }
    // store + BN partials
    float ps[4] = {0, 0, 0, 0}, pq[4] = {0, 0, 0, 0};
    float* Yg = Y1 + (size_t)g * 64 * 128;
#pragma unroll
    for (int i = 0; i < 8; ++i) {
        float4 v = make_float4(acy[i][0], acy[i][1], acy[i][2], acy[i][3]);
        *(float4*)&Yg[(ty * 8 + i) * 128 + tx * 4] = v;
#pragma unroll
        for (int j = 0; j < 4; ++j) { ps[j] += acy[i][j]; pq[j] += acy[i][j] * acy[i][j]; }
    }
    __syncthreads();   // all H reads done before reuse as reduction area
    float* redS = Xh;
    float* redQ = Xh + 1024;
#pragma unroll
    for (int j = 0; j < 4; ++j) {
        redS[ty * 128 + tx * 4 + j] = ps[j];
        redQ[ty * 128 + tx * 4 + j] = pq[j];
    }
    __syncthreads();
    if (t < 128) {
        float S = 0.f, Q = 0.f;
        for (int y = 0; y < 8; ++y) { S += redS[y * 128 + t]; Q += redQ[y * 128 + t]; }
        atomicAdd(&bn1S[t], (double)S);
        atomicAdd(&bn1Q[t], (double)Q);
    }
}

// ---------------- BN finalize (shared by bn1/bn2) ----------------
__global__ void k_bnfin(const double* __restrict__ S, const double* __restrict__ Q,
                        const float* __restrict__ gam, const float* __restrict__ bet,
                        float* __restrict__ scale, float* __restrict__ shift, double invN) {
    int t = threadIdx.x;
    double m = S[t] * invN;
    double v = Q[t] * invN - m * m;
    double rstd = 1.0 / sqrt(v + 1e-5);
    float sc = (float)((double)gam[t] * rstd);
    scale[t] = sc;
    shift[t] = bet[t] - (float)m * sc;
}

// ---------------- K3a: BN1+PReLU, pooling score, top-k, H2 = (s*Xkept)@W2 ----------------
// (R14/R16 measured-good version, untouched.)
__global__ __launch_bounds__(256, 2)
void k3a_pool(float* __restrict__ Y1, const float* __restrict__ scale1,
              const float* __restrict__ shift1, const float* __restrict__ a1,
              const float* __restrict__ Wp, const float* __restrict__ bp,
              const float* __restrict__ AP, const float* __restrict__ W2) {
    __shared__ float Xs[64 * 132];      // x rows, stride 132
    __shared__ float slin[64], psum[256], score[64];
    __shared__ int   rnk[64], ord[64];
    int g = blockIdx.x, t = threadIdx.x;
    int tx = t & 31, ty = t >> 5;
    float alpha1 = a1[0];

    float* slab = Y1 + (size_t)g * 8192;
    {   // float4 staging: f4 = t&31 is fixed per thread -> scale/shift loaded once
        const float4* Yg4 = (const float4*)slab;
        float4 sc4 = *(const float4*)&scale1[tx * 4];
        float4 sh4 = *(const float4*)&shift1[tx * 4];
#pragma unroll
        for (int it = 0; it < 8; ++it) {
            int e4 = it * 256 + t;       // float4 index, 32 per row
            int c = e4 >> 5;
            float4 v = Yg4[e4];
            v.x = v.x * sc4.x + sh4.x; v.x = (v.x >= 0.f) ? v.x : alpha1 * v.x;
            v.y = v.y * sc4.y + sh4.y; v.y = (v.y >= 0.f) ? v.y : alpha1 * v.y;
            v.z = v.z * sc4.z + sh4.z; v.z = (v.z >= 0.f) ? v.z : alpha1 * v.z;
            v.w = v.w * sc4.w + sh4.w; v.w = (v.w >= 0.f) ? v.w : alpha1 * v.w;
            *(float4*)&Xs[c * 132 + tx * 4] = v;
        }
    }
    __syncthreads();
    // pooling: slin = X @ Wp  (4 threads per row)
    {
        int rr = t >> 2, q4 = t & 3;
        float sp = 0.f;
        for (int m = 0; m < 32; ++m) sp += Xs[rr * 132 + q4 * 32 + m] * Wp[q4 * 32 + m];
        psum[t] = sp;
    }
    __syncthreads();
    if (t < 64) slin[t] = psum[t * 4] + psum[t * 4 + 1] + psum[t * 4 + 2] + psum[t * 4 + 3];
    __syncthreads();
    // score matvec, parallel over 256 threads: node n = t>>2, quarter q = t&3
    {
        int n = t >> 2, q = t & 3;
        float acc = 0.f;
#pragma unroll
        for (int m = 0; m < 16; ++m) acc += AP[n * 64 + q * 16 + m] * slin[q * 16 + m];
        psum[t] = acc;
    }
    __syncthreads();
    if (t < 64) score[t] = tanhf(bp[0] + psum[t * 4] + psum[t * 4 + 1] + psum[t * 4 + 2] + psum[t * 4 + 3]);
    __syncthreads();
    // rank, parallel over 256 threads: node n = t>>2 counts c2 in its 16-chunk
    {
        int n = t >> 2, q = t & 3;
        float sc = score[n];
        int cnt = 0;
#pragma unroll
        for (int m = 0; m < 16; ++m) {
            int c2 = q * 16 + m;
            float o = score[c2];
            cnt += (o > sc) || (o == sc && c2 < n);  // stable descending rank (top_k tie rule)
        }
        psum[t] = (float)cnt;
    }
    __syncthreads();
    if (t < 64) {
        int cnt = (int)(psum[t * 4] + psum[t * 4 + 1] + psum[t * 4 + 2] + psum[t * 4 + 3]);
        rnk[t] = cnt;
        if (cnt < Kc) ord[cnt] = t;
        ((int*)(slab + 4096))[t] = cnt;              // rnk -> global slab
    }
    __syncthreads();

    // H2[r][o] = score[ord[r]] * sum_k Xs[ord[r]][k] * W2[k][o]   (rows >= Kc are zero)
    {
        int row0 = ty * 8;
        float acc2[8][2];
        int   cidx[8];
        float srow[8];
#pragma unroll
        for (int i = 0; i < 8; ++i) {
            acc2[i][0] = 0.f; acc2[i][1] = 0.f;
            int r = row0 + i;
            if (r < Kc) { cidx[i] = ord[r]; srow[i] = score[cidx[i]]; }
            else        { cidx[i] = 0;      srow[i] = 0.f; }
        }
        for (int k0 = 0; k0 < 128; k0 += 4) {
            float4 xv[8];
#pragma unroll
            for (int i = 0; i < 8; ++i) xv[i] = *(const float4*)&Xs[cidx[i] * 132 + k0];
#pragma unroll
            for (int q = 0; q < 4; ++q) {
                float2 w = *(const float2*)&W2[(k0 + q) * 64 + tx * 2];
#pragma unroll
                for (int i = 0; i < 8; ++i) {
                    float xq = (q == 0) ? xv[i].x : (q == 1) ? xv[i].y : (q == 2) ? xv[i].z : xv[i].w;
                    acc2[i][0] += xq * w.x;
                    acc2[i][1] += xq * w.y;
                }
            }
        }
        // write H2 to the global slab (coalesced float2; rows >= Kc get zeros)
#pragma unroll
        for (int i = 0; i < 8; ++i) {
            *(float2*)&slab[(row0 + i) * 64 + tx * 2] =
                make_float2(acc2[i][0] * srow[i], acc2[i][1] * srow[i]);
        }
    }
}

// ---------------- K3b: build A2, Y2 = A2@H2 + b2, BN2 partials ----------------
// (Measured-good R7 version, untouched.)
__global__ __launch_bounds__(256, 2)
void k3b_gc2(const float* __restrict__ Y1, const int* __restrict__ ei,
             const float* __restrict__ ew, const float* __restrict__ b2,
             float* __restrict__ Y2, double* bn2S, double* bn2Q) {
    __shared__ float H2s[64 * 68];      // stride 68 (16B-aligned rows)
    __shared__ float A2s[4096];
    __shared__ float dis2[64], deg2[64];
    __shared__ int   rnk[64];
    int g = blockIdx.x, t = threadIdx.x;
    int tx = t & 31, ty = t >> 5;

    const float* slab = Y1 + (size_t)g * 8192;
    {   // stage H2 (coalesced float4 reads, 64 rows x 64)
        const float4* src = (const float4*)slab;
#pragma unroll
        for (int it = 0; it < 4; ++it) {
            int i4 = it * 256 + t;
            int r = i4 >> 4, c4 = i4 & 15;
            *(float4*)&H2s[r * 68 + c4 * 4] = src[i4];
        }
    }
    if (t < 64) rnk[t] = ((const int*)(slab + 4096))[t];
    {
        float4 z = make_float4(0.f, 0.f, 0.f, 0.f);
        float4* A2s4 = (float4*)A2s;
#pragma unroll
        for (int j = 0; j < 4; ++j) A2s4[j * 256 + t] = z;
    }
    if (t < 64) deg2[t] = 1.0f;        // self-loop
    __syncthreads();
    for (int e = t; e < Ec; e += 256) {
        int r = ei[e], c = ei[Ec + e];
        if (rnk[r] < Kc && rnk[c] < Kc) atomicAdd(&deg2[rnk[c]], ew[e]);
    }
    __syncthreads();
    if (t < 64) dis2[t] = 1.0f / sqrtf(deg2[t]);
    __syncthreads();
    for (int e = t; e < Ec; e += 256) {
        int r = ei[e], c = ei[Ec + e];
        int rkr = rnk[r], rkc = rnk[c];
        if (rkr < Kc && rkc < Kc) atomicAdd(&A2s[rkc * 64 + rkr], dis2[rkr] * ew[e] * dis2[rkc]);
    }
    __syncthreads();
    if (t < Kc) A2s[t * 65] += dis2[t] * dis2[t];
    __syncthreads();

    // Y2 = A2s * H2 + b2
    float acy[8][2];
    float2 b2v = *(const float2*)&b2[tx * 2];
#pragma unroll
    for (int i = 0; i < 8; ++i) { acy[i][0] = b2v.x; acy[i][1] = b2v.y; }
    for (int rr = 0; rr < 16; ++rr) {
        float2 h2[4];
#pragma unroll
        for (int q = 0; q < 4; ++q) h2[q] = *(const float2*)&H2s[(rr * 4 + q) * 68 + tx * 2];
#pragma unroll
        for (int i = 0; i < 8; ++i) {
            float4 a4 = *(const float4*)&A2s[(ty * 8 + i) * 64 + rr * 4];
            acy[i][0] += a4.x * h2[0].x + a4.y * h2[1].x + a4.z * h2[2].x + a4.w * h2[3].x;
            acy[i][1] += a4.x * h2[0].y + a4.y * h2[1].y + a4.z * h2[2].y + a4.w * h2[3].y;
        }
    }
    float s0 = 0.f, s1 = 0.f, q0 = 0.f, q1 = 0.f;
    float* Y2g = Y2 + (size_t)g * Kc * 64;
#pragma unroll
    for (int i = 0; i < 8; ++i) {
        int ck = ty * 8 + i;
        if (ck < Kc) {
            float2 v = make_float2(acy[i][0], acy[i][1]);
            *(float2*)&Y2g[ck * 64 + tx * 2] = v;
            s0 += v.x; s1 += v.y; q0 += v.x * v.x; q1 += v.y * v.y;
        }
    }
    __syncthreads();   // all H2s reads done before reuse as reduction area
    float* redS = H2s;
    float* redQ = H2s + 512;
    redS[ty * 64 + tx * 2]     = s0;
    redS[ty * 64 + tx * 2 + 1] = s1;
    redQ[ty * 64 + tx * 2]     = q0;
    redQ[ty * 64 + tx * 2 + 1] = q1;
    __syncthreads();
    if (t < 64) {
        float S = 0.f, Q = 0.f;
        for (int y = 0; y < 8; ++y) { S += redS[y * 64 + t]; Q += redQ[y * 64 + t]; }
        atomicAdd(&bn2S[t], (double)S);
        atomicAdd(&bn2Q[t], (double)Q);
    }
}

// ---------------- K5: final BN2+PReLU, write x2 and z_seq ----------------
__global__ void k5_out(const float* __restrict__ Y2, const float* __restrict__ scale2,
                       const float* __restrict__ shift2, const float* __restrict__ a2v,
                       float* __restrict__ out) {
    __shared__ float red[4 * 64];
    int g = blockIdx.x, t = threadIdx.x;
    float alpha = a2v[0];
    const float* Yg = Y2 + (size_t)g * Kc * 64;
    float* Og = out + (size_t)g * Kc * 64;
    int c = t & 63, rg = t >> 6;
    float part = 0.f;
    for (int rk = rg; rk < Kc; rk += 4) {
        float v = Yg[rk * 64 + c] * scale2[c] + shift2[c];
        v = (v >= 0.f) ? v : alpha * v;
        Og[rk * 64 + c] = v;
        part += v;
    }
    red[rg * 64 + c] = part;
    __syncthreads();
    if (t < 64) {
        float z = (red[t] + red[64 + t] + red[128 + t] + red[192 + t]) / (float)Kc;
        int b = g / TPc, tp = g % TPc;
        out[(size_t)Nkc * 64 + (size_t)b * NOUTc * TPc + t * TPc + tp] = z;
    }
}

extern "C" void kernel_launch(void* const* d_in, const int* in_sizes, int n_in,
                              void* d_out, int out_size, void* d_ws, size_t ws_size,
                              hipStream_t stream) {
    const float* h   = (const float*)d_in[0];
    const int*   ei  = (const int*)  d_in[1];
    const float* ew  = (const float*)d_in[2];
    const float* W1  = (const float*)d_in[3];
    const float* b1  = (const float*)d_in[4];
    const float* g1  = (const float*)d_in[5];
    const float* be1 = (const float*)d_in[6];
    const float* a1  = (const float*)d_in[7];
    const float* Wp  = (const float*)d_in[8];
    const float* bp  = (const float*)d_in[9];
    const float* W2  = (const float*)d_in[10];
    const float* b2  = (const float*)d_in[11];
    const float* g2  = (const float*)d_in[12];
    const float* be2 = (const float*)d_in[13];
    const float* a2  = (const float*)d_in[14];

    char* ws = (char*)d_ws;
    double* bn1S   = (double*)(ws + 0);
    double* bn1Q   = (double*)(ws + 1024);
    double* bn2S   = (double*)(ws + 2048);
    double* bn2Q   = (double*)(ws + 2560);
    float*  scale1 = (float*)(ws + 3072);
    float*  shift1 = (float*)(ws + 3584);
    float*  scale2 = (float*)(ws + 4096);
    float*  shift2 = (float*)(ws + 4352);
    float*  A1     = (float*)(ws + 4608);
    float*  AP     = (float*)(ws + 20992);
    float*  XT     = (float*)(ws + 37376);                 // [g][f][c] = 52428800 B
    float*  Y1     = XT;                                   // in-place; k3a also writes H2+rnk into slab fronts
    float*  Y2     = (float*)(ws + 37376 + 52428800);      // Nk*64 f32 = 23756800 B
    float*  out    = (float*)d_out;

    hipLaunchKernelGGL(k0_prep, dim3(1), dim3(256), 0, stream,
                       ei, ew, A1, AP, bn1S, bn1Q, bn2S, bn2Q);
    hipLaunchKernelGGL(k_trans, dim3(2048), dim3(256), 0, stream, h, XT);
    hipLaunchKernelGGL(k1_gc1, dim3(Gc), dim3(256), 0, stream,
                       XT, W1, b1, A1, Y1, bn1S, bn1Q);
    hipLaunchKernelGGL(k_bnfin, dim3(1), dim3(128), 0, stream,
                       bn1S, bn1Q, g1, be1, scale1, shift1, 1.0 / (double)Nc);
    hipLaunchKernelGGL(k3a_pool, dim3(Gc), dim3(256), 0, stream,
                       Y1, scale1, shift1, a1, Wp, bp, AP, W2);
    hipLaunchKernelGGL(k3b_gc2, dim3(Gc), dim3(256), 0, stream,
                       Y1, ei, ew, b2, Y2, bn2S, bn2Q);
    hipLaunchKernelGGL(k_bnfin, dim3(1), dim3(64), 0, stream,
                       bn2S, bn2Q, g2, be2, scale2, shift2, 1.0 / (double)Nkc);
    hipLaunchKernelGGL(k5_out, dim3(Gc), dim3(256), 0, stream,
                       Y2, scale2, shift2, a2, out);
}

// Round 19
// 213.427 us; speedup vs baseline: 2.1682x; 1.0254x over previous
//
#include <hip/hip_runtime.h>

// Problem constants
constexpr int Bc   = 16;
constexpr int Cc   = 64;
constexpr int Fc   = 128;
constexpr int TPc  = 100;
constexpr int Gc   = Bc * TPc;      // 1600 graphs
constexpr int Nc   = Gc * Cc;       // 102400 nodes
constexpr int Ec   = 576;
constexpr int NHID = 128;
constexpr int NOUTc= 64;
constexpr int Kc   = 58;            // ceil(0.9*64)
constexpr int Nkc  = Gc * Kc;       // 92800

// ---------------- K_trans (+ fused k0 in block 2048) ----------------
// blocks 0..2047: h[b][c][f][tp] -> XT[g=b*100+tp][f][c] (verbatim R16 body).
// block 2048: build A1/AP + zero BN accumulators (verbatim k0 body, LDS overlaid)
// -> overlaps the transpose instead of serializing as a 1-block kernel.
__global__ __launch_bounds__(256)
void k_trans(const float* __restrict__ h, float* __restrict__ XT,
             const int* __restrict__ ei, const float* __restrict__ ew,
             float* __restrict__ A1, float* __restrict__ AP,
             double* bn1S, double* bn1Q, double* bn2S, double* bn2Q) {
    __shared__ float S[8448];   // transpose: tile[6464] ; k0: A1L[4096]+APL[4096]+deg/dis[256]
    int t = threadIdx.x;
    if (blockIdx.x == 2048) {
        float* A1L  = S;
        float* APL  = S + 4096;
        float* deg1 = S + 8192;
        float* degP = S + 8256;
        float* dis1 = S + 8320;
        float* disP = S + 8384;
        if (t < 64) { deg1[t] = 1.0f; degP[t] = 1.0f; }   // self-loop weight 1
        for (int i = t; i < 4096; i += 256) { A1L[i] = 0.f; APL[i] = 0.f; }
        if (t < 128) { bn1S[t] = 0.0; bn1Q[t] = 0.0; }
        if (t < 64)  { bn2S[t] = 0.0; bn2Q[t] = 0.0; }
        __syncthreads();
        for (int e = t; e < Ec; e += 256) {
            int c = ei[Ec + e];
            atomicAdd(&deg1[c], ew[e]);
            atomicAdd(&degP[c], 1.0f);
        }
        __syncthreads();
        if (t < 64) { dis1[t] = 1.0f / sqrtf(deg1[t]); disP[t] = 1.0f / sqrtf(degP[t]); }
        __syncthreads();
        for (int e = t; e < Ec; e += 256) {
            int r = ei[e], c = ei[Ec + e];
            atomicAdd(&A1L[c * 64 + r], dis1[r] * ew[e] * dis1[c]);
            atomicAdd(&APL[c * 64 + r], disP[r] * disP[c]);
        }
        __syncthreads();
        if (t < 64) {
            A1L[t * 65] += dis1[t] * dis1[t];
            APL[t * 65] += disP[t] * disP[t];
        }
        __syncthreads();
        for (int i = t; i < 4096; i += 256) { A1[i] = A1L[i]; AP[i] = APL[i]; }
        return;
    }
    float* tile = S;                   // [c][tp], stride 101
    int blk = blockIdx.x;              // 0..2047
    int b = blk >> 7, f = blk & 127;
    const float* hb = h + (size_t)b * 819200 + (size_t)f * 100;
    for (int i = t; i < 6400; i += 256) {
        unsigned c = (unsigned)i / 100u;
        unsigned tp = (unsigned)i - c * 100u;
        tile[c * 101 + tp] = hb[(size_t)c * 12800 + tp];
    }
    __syncthreads();
    float* xb = XT + (size_t)b * 100 * 8192 + f * 64;
    for (int j = t; j < 6400; j += 256) {
        int tp = j >> 6, c = j & 63;
        xb[(size_t)tp * 8192 + c] = tile[c * 101 + tp];
    }
}

// ---------------- K1: per-graph gc1 = A1*(X*W1)+b1, BN1 partial sums ----------------
// EXACT R12/R16 measured-good version (80 us, 256 thr, VGPR 64, no spill).
// PLATEAUED -- five variants failed (R9/R11/R13/R15/R17). DO NOT TOUCH.
__global__ __launch_bounds__(256, 4)
void k1_gc1(const float* __restrict__ XT, const float* __restrict__ W1,
            const float* __restrict__ b1, const float* __restrict__ A1,
            float* __restrict__ Y1, double* bn1S, double* bn1Q) {
    __shared__ float Xh[8192];    // phase A: X quarter [0..2047] + W1 quarter [2048..6143]
                                  // phase B: H [c=64][f=128] (full 32KB); then BN reduction
    int g = blockIdx.x;
    int t = threadIdx.x;
    int tx = t & 31, ty = t >> 5;

    float acc[8][4];
#pragma unroll
    for (int i = 0; i < 8; ++i)
#pragma unroll
        for (int j = 0; j < 4; ++j) acc[i][j] = 0.f;

    for (int kq = 0; kq < 4; ++kq) {
        __syncthreads();  // protects stage buffers across kq iterations
        {   // X quarter: XT slab is [k][c] -> quarter kq is a contiguous 8KB run
            const float4* xsrc = (const float4*)(XT + (size_t)g * 8192 + kq * 2048);
            float4* xdst = (float4*)Xh;
            xdst[t]       = xsrc[t];
            xdst[256 + t] = xsrc[256 + t];
            // W1 quarter: rows kq*32..kq*32+31, contiguous 16KB run
            const float4* wsrc = (const float4*)(W1 + kq * 4096);
            float4* wdst = (float4*)(Xh + 2048);
#pragma unroll
            for (int it = 0; it < 4; ++it) wdst[it * 256 + t] = wsrc[it * 256 + t];
        }
        __syncthreads();
        for (int kk = 0; kk < 32; ++kk) {
            float4 x0 = *(const float4*)&Xh[kk * 64 + ty * 8];
            float4 x1 = *(const float4*)&Xh[kk * 64 + ty * 8 + 4];
            float4 w  = *(const float4*)&Xh[2048 + kk * 128 + tx * 4];
            float xr[8] = {x0.x, x0.y, x0.z, x0.w, x1.x, x1.y, x1.z, x1.w};
#pragma unroll
            for (int i = 0; i < 8; ++i) {
                acc[i][0] += xr[i] * w.x;
                acc[i][1] += xr[i] * w.y;
                acc[i][2] += xr[i] * w.z;
                acc[i][3] += xr[i] * w.w;
            }
        }
    }
    __syncthreads();   // all stage-buffer reads done
    // H -> Xh (full 32KB), layout [c][f] stride 128
#pragma unroll
    for (int i = 0; i < 8; ++i) {
        float4 v = make_float4(acc[i][0], acc[i][1], acc[i][2], acc[i][3]);
        *(float4*)&Xh[(ty * 8 + i) * 128 + tx * 4] = v;
    }
    __syncthreads();
    // GEMM2: Y = A1 * H + b1  (A1 from global: ty-uniform float4, L1-resident)
    float acy[8][4];
    float4 bb = *(const float4*)&b1[tx * 4];
#pragma unroll
    for (int i = 0; i < 8; ++i) { acy[i][0] = bb.x; acy[i][1] = bb.y; acy[i][2] = bb.z; acy[i][3] = bb.w; }
    for (int rr = 0; rr < 16; ++rr) {
        float4 hrow[4];
#pragma unroll
        for (int q = 0; q < 4; ++q) hrow[q] = *(const float4*)&Xh[(rr * 4 + q) * 128 + tx * 4];
#pragma unroll
        for (int i = 0; i < 8; ++i) {
            float4 a4 = *(const float4*)&A1[(ty * 8 + i) * 64 + rr * 4];
            acy[i][0] += a4.x * hrow[0].x + a4.y * hrow[1].x + a4.z * hrow[2].x + a4.w * hrow[3].x;
            acy[i][1] += a4.x * hrow[0].y + a4.y * hrow[1].y + a4.z * hrow[2].y + a4.w * hrow[3].y;
            acy[i][2] += a4.x * hrow[0].z + a4.y * hrow[1].z + a4.z * hrow[2].z + a4.w * hrow[3].z;
            acy[i][3] += a4.x * hrow[0].w + a4.y * hrow[1].w + a4.z * hrow[2].w + a4.w * hrow[3].w;
        }
    }
    // store + BN partials
    float ps[4] = {0, 0, 0, 0}, pq[4] = {0, 0, 0, 0};
    float* Yg = Y1 + (size_t)g * 64 * 128;
#pragma unroll
    for (int i = 0; i < 8; ++i) {
        float4 v = make_float4(acy[i][0], acy[i][1], acy[i][2], acy[i][3]);
        *(float4*)&Yg[(ty * 8 + i) * 128 + tx * 4] = v;
#pragma unroll
        for (int j = 0; j < 4; ++j) { ps[j] += acy[i][j]; pq[j] += acy[i][j] * acy[i][j]; }
    }
    __syncthreads();   // all H reads done before reuse as reduction area
    float* redS = Xh;
    float* redQ = Xh + 1024;
#pragma unroll
    for (int j = 0; j < 4; ++j) {
        redS[ty * 128 + tx * 4 + j] = ps[j];
        redQ[ty * 128 + tx * 4 + j] = pq[j];
    }
    __syncthreads();
    if (t < 128) {
        float Sv = 0.f, Q = 0.f;
        for (int y = 0; y < 8; ++y) { Sv += redS[y * 128 + t]; Q += redQ[y * 128 + t]; }
        atomicAdd(&bn1S[t], (double)Sv);
        atomicAdd(&bn1Q[t], (double)Q);
    }
}

// ---------------- K3a: BN1 finalize (inlined) + PReLU, pooling, top-k, H2 ----------------
// R16 measured-good body with ONE plumbing change: scale1/shift1 computed per-block
// from bn1S/bn1Q into LDS (replaces the 1-block k_bnfin launch).
__global__ __launch_bounds__(256, 2)
void k3a_pool(float* __restrict__ Y1, const double* __restrict__ bn1S,
              const double* __restrict__ bn1Q, const float* __restrict__ g1,
              const float* __restrict__ be1, const float* __restrict__ a1,
              const float* __restrict__ Wp, const float* __restrict__ bp,
              const float* __restrict__ AP, const float* __restrict__ W2) {
    __shared__ float Xs[64 * 132];      // x rows, stride 132
    __shared__ float slin[64], psum[256], score[64];
    __shared__ float scl[128], shf[128];
    __shared__ int   rnk[64], ord[64];
    int g = blockIdx.x, t = threadIdx.x;
    int tx = t & 31, ty = t >> 5;
    float alpha1 = a1[0];

    // BN1 finalize (was k_bnfin): per-block recompute, ~10 double ops / thread
    if (t < 128) {
        double m = bn1S[t] * (1.0 / (double)Nc);
        double v = bn1Q[t] * (1.0 / (double)Nc) - m * m;
        double rstd = 1.0 / sqrt(v + 1e-5);
        float sc = (float)((double)g1[t] * rstd);
        scl[t] = sc;
        shf[t] = be1[t] - (float)m * sc;
    }
    __syncthreads();

    float* slab = Y1 + (size_t)g * 8192;
    {   // float4 staging: f4 = t&31 is fixed per thread -> scale/shift loaded once
        const float4* Yg4 = (const float4*)slab;
        float4 sc4 = *(const float4*)&scl[tx * 4];
        float4 sh4 = *(const float4*)&shf[tx * 4];
#pragma unroll
        for (int it = 0; it < 8; ++it) {
            int e4 = it * 256 + t;       // float4 index, 32 per row
            int c = e4 >> 5;
            float4 v = Yg4[e4];
            v.x = v.x * sc4.x + sh4.x; v.x = (v.x >= 0.f) ? v.x : alpha1 * v.x;
            v.y = v.y * sc4.y + sh4.y; v.y = (v.y >= 0.f) ? v.y : alpha1 * v.y;
            v.z = v.z * sc4.z + sh4.z; v.z = (v.z >= 0.f) ? v.z : alpha1 * v.z;
            v.w = v.w * sc4.w + sh4.w; v.w = (v.w >= 0.f) ? v.w : alpha1 * v.w;
            *(float4*)&Xs[c * 132 + tx * 4] = v;
        }
    }
    __syncthreads();
    // pooling: slin = X @ Wp  (4 threads per row)
    {
        int rr = t >> 2, q4 = t & 3;
        float sp = 0.f;
        for (int m = 0; m < 32; ++m) sp += Xs[rr * 132 + q4 * 32 + m] * Wp[q4 * 32 + m];
        psum[t] = sp;
    }
    __syncthreads();
    if (t < 64) slin[t] = psum[t * 4] + psum[t * 4 + 1] + psum[t * 4 + 2] + psum[t * 4 + 3];
    __syncthreads();
    // score matvec, parallel over 256 threads: node n = t>>2, quarter q = t&3
    {
        int n = t >> 2, q = t & 3;
        float acc = 0.f;
#pragma unroll
        for (int m = 0; m < 16; ++m) acc += AP[n * 64 + q * 16 + m] * slin[q * 16 + m];
        psum[t] = acc;
    }
    __syncthreads();
    if (t < 64) score[t] = tanhf(bp[0] + psum[t * 4] + psum[t * 4 + 1] + psum[t * 4 + 2] + psum[t * 4 + 3]);
    __syncthreads();
    // rank, parallel over 256 threads: node n = t>>2 counts c2 in its 16-chunk
    {
        int n = t >> 2, q = t & 3;
        float sc = score[n];
        int cnt = 0;
#pragma unroll
        for (int m = 0; m < 16; ++m) {
            int c2 = q * 16 + m;
            float o = score[c2];
            cnt += (o > sc) || (o == sc && c2 < n);  // stable descending rank (top_k tie rule)
        }
        psum[t] = (float)cnt;
    }
    __syncthreads();
    if (t < 64) {
        int cnt = (int)(psum[t * 4] + psum[t * 4 + 1] + psum[t * 4 + 2] + psum[t * 4 + 3]);
        rnk[t] = cnt;
        if (cnt < Kc) ord[cnt] = t;
        ((int*)(slab + 4096))[t] = cnt;              // rnk -> global slab
    }
    __syncthreads();

    // H2[r][o] = score[ord[r]] * sum_k Xs[ord[r]][k] * W2[k][o]   (rows >= Kc are zero)
    {
        int row0 = ty * 8;
        float acc2[8][2];
        int   cidx[8];
        float srow[8];
#pragma unroll
        for (int i = 0; i < 8; ++i) {
            acc2[i][0] = 0.f; acc2[i][1] = 0.f;
            int r = row0 + i;
            if (r < Kc) { cidx[i] = ord[r]; srow[i] = score[cidx[i]]; }
            else        { cidx[i] = 0;      srow[i] = 0.f; }
        }
        for (int k0 = 0; k0 < 128; k0 += 4) {
            float4 xv[8];
#pragma unroll
            for (int i = 0; i < 8; ++i) xv[i] = *(const float4*)&Xs[cidx[i] * 132 + k0];
#pragma unroll
            for (int q = 0; q < 4; ++q) {
                float2 w = *(const float2*)&W2[(k0 + q) * 64 + tx * 2];
#pragma unroll
                for (int i = 0; i < 8; ++i) {
                    float xq = (q == 0) ? xv[i].x : (q == 1) ? xv[i].y : (q == 2) ? xv[i].z : xv[i].w;
                    acc2[i][0] += xq * w.x;
                    acc2[i][1] += xq * w.y;
                }
            }
        }
        // write H2 to the global slab (coalesced float2; rows >= Kc get zeros)
#pragma unroll
        for (int i = 0; i < 8; ++i) {
            *(float2*)&slab[(row0 + i) * 64 + tx * 2] =
                make_float2(acc2[i][0] * srow[i], acc2[i][1] * srow[i]);
        }
    }
}

// ---------------- K3b: build A2, Y2 = A2@H2 + b2, BN2 partials ----------------
// (Measured-good R7 version, untouched.)
__global__ __launch_bounds__(256, 2)
void k3b_gc2(const float* __restrict__ Y1, const int* __restrict__ ei,
             const float* __restrict__ ew, const float* __restrict__ b2,
             float* __restrict__ Y2, double* bn2S, double* bn2Q) {
    __shared__ float H2s[64 * 68];      // stride 68 (16B-aligned rows)
    __shared__ float A2s[4096];
    __shared__ float dis2[64], deg2[64];
    __shared__ int   rnk[64];
    int g = blockIdx.x, t = threadIdx.x;
    int tx = t & 31, ty = t >> 5;

    const float* slab = Y1 + (size_t)g * 8192;
    {   // stage H2 (coalesced float4 reads, 64 rows x 64)
        const float4* src = (const float4*)slab;
#pragma unroll
        for (int it = 0; it < 4; ++it) {
            int i4 = it * 256 + t;
            int r = i4 >> 4, c4 = i4 & 15;
            *(float4*)&H2s[r * 68 + c4 * 4] = src[i4];
        }
    }
    if (t < 64) rnk[t] = ((const int*)(slab + 4096))[t];
    {
        float4 z = make_float4(0.f, 0.f, 0.f, 0.f);
        float4* A2s4 = (float4*)A2s;
#pragma unroll
        for (int j = 0; j < 4; ++j) A2s4[j * 256 + t] = z;
    }
    if (t < 64) deg2[t] = 1.0f;        // self-loop
    __syncthreads();
    for (int e = t; e < Ec; e += 256) {
        int r = ei[e], c = ei[Ec + e];
        if (rnk[r] < Kc && rnk[c] < Kc) atomicAdd(&deg2[rnk[c]], ew[e]);
    }
    __syncthreads();
    if (t < 64) dis2[t] = 1.0f / sqrtf(deg2[t]);
    __syncthreads();
    for (int e = t; e < Ec; e += 256) {
        int r = ei[e], c = ei[Ec + e];
        int rkr = rnk[r], rkc = rnk[c];
        if (rkr < Kc && rkc < Kc) atomicAdd(&A2s[rkc * 64 + rkr], dis2[rkr] * ew[e] * dis2[rkc]);
    }
    __syncthreads();
    if (t < Kc) A2s[t * 65] += dis2[t] * dis2[t];
    __syncthreads();

    // Y2 = A2s * H2 + b2
    float acy[8][2];
    float2 b2v = *(const float2*)&b2[tx * 2];
#pragma unroll
    for (int i = 0; i < 8; ++i) { acy[i][0] = b2v.x; acy[i][1] = b2v.y; }
    for (int rr = 0; rr < 16; ++rr) {
        float2 h2[4];
#pragma unroll
        for (int q = 0; q < 4; ++q) h2[q] = *(const float2*)&H2s[(rr * 4 + q) * 68 + tx * 2];
#pragma unroll
        for (int i = 0; i < 8; ++i) {
            float4 a4 = *(const float4*)&A2s[(ty * 8 + i) * 64 + rr * 4];
            acy[i][0] += a4.x * h2[0].x + a4.y * h2[1].x + a4.z * h2[2].x + a4.w * h2[3].x;
            acy[i][1] += a4.x * h2[0].y + a4.y * h2[1].y + a4.z * h2[2].y + a4.w * h2[3].y;
        }
    }
    float s0 = 0.f, s1 = 0.f, q0 = 0.f, q1 = 0.f;
    float* Y2g = Y2 + (size_t)g * Kc * 64;
#pragma unroll
    for (int i = 0; i < 8; ++i) {
        int ck = ty * 8 + i;
        if (ck < Kc) {
            float2 v = make_float2(acy[i][0], acy[i][1]);
            *(float2*)&Y2g[ck * 64 + tx * 2] = v;
            s0 += v.x; s1 += v.y; q0 += v.x * v.x; q1 += v.y * v.y;
        }
    }
    __syncthreads();   // all H2s reads done before reuse as reduction area
    float* redS = H2s;
    float* redQ = H2s + 512;
    redS[ty * 64 + tx * 2]     = s0;
    redS[ty * 64 + tx * 2 + 1] = s1;
    redQ[ty * 64 + tx * 2]     = q0;
    redQ[ty * 64 + tx * 2 + 1] = q1;
    __syncthreads();
    if (t < 64) {
        float S = 0.f, Q = 0.f;
        for (int y = 0; y < 8; ++y) { S += redS[y * 64 + t]; Q += redQ[y * 64 + t]; }
        atomicAdd(&bn2S[t], (double)S);
        atomicAdd(&bn2Q[t], (double)Q);
    }
}

// ---------------- K5: BN2 finalize (inlined) + PReLU, write x2 and z_seq ----------------
__global__ void k5_out(const float* __restrict__ Y2, const double* __restrict__ bn2S,
                       const double* __restrict__ bn2Q, const float* __restrict__ g2,
                       const float* __restrict__ be2, const float* __restrict__ a2v,
                       float* __restrict__ out) {
    __shared__ float red[4 * 64];
    __shared__ float scl[64], shf[64];
    int g = blockIdx.x, t = threadIdx.x;
    float alpha = a2v[0];
    // BN2 finalize (was k_bnfin): per-block recompute
    if (t < 64) {
        double m = bn2S[t] * (1.0 / (double)Nkc);
        double v = bn2Q[t] * (1.0 / (double)Nkc) - m * m;
        double rstd = 1.0 / sqrt(v + 1e-5);
        float sc = (float)((double)g2[t] * rstd);
        scl[t] = sc;
        shf[t] = be2[t] - (float)m * sc;
    }
    __syncthreads();
    const float* Yg = Y2 + (size_t)g * Kc * 64;
    float* Og = out + (size_t)g * Kc * 64;
    int c = t & 63, rg = t >> 6;
    float part = 0.f;
    for (int rk = rg; rk < Kc; rk += 4) {
        float v = Yg[rk * 64 + c] * scl[c] + shf[c];
        v = (v >= 0.f) ? v : alpha * v;
        Og[rk * 64 + c] = v;
        part += v;
    }
    red[rg * 64 + c] = part;
    __syncthreads();
    if (t < 64) {
        float z = (red[t] + red[64 + t] + red[128 + t] + red[192 + t]) / (float)Kc;
        int b = g / TPc, tp = g % TPc;
        out[(size_t)Nkc * 64 + (size_t)b * NOUTc * TPc + t * TPc + tp] = z;
    }
}

extern "C" void kernel_launch(void* const* d_in, const int* in_sizes, int n_in,
                              void* d_out, int out_size, void* d_ws, size_t ws_size,
                              hipStream_t stream) {
    const float* h   = (const float*)d_in[0];
    const int*   ei  = (const int*)  d_in[1];
    const float* ew  = (const float*)d_in[2];
    const float* W1  = (const float*)d_in[3];
    const float* b1  = (const float*)d_in[4];
    const float* g1  = (const float*)d_in[5];
    const float* be1 = (const float*)d_in[6];
    const float* a1  = (const float*)d_in[7];
    const float* Wp  = (const float*)d_in[8];
    const float* bp  = (const float*)d_in[9];
    const float* W2  = (const float*)d_in[10];
    const float* b2  = (const float*)d_in[11];
    const float* g2  = (const float*)d_in[12];
    const float* be2 = (const float*)d_in[13];
    const float* a2  = (const float*)d_in[14];

    char* ws = (char*)d_ws;
    double* bn1S   = (double*)(ws + 0);
    double* bn1Q   = (double*)(ws + 1024);
    double* bn2S   = (double*)(ws + 2048);
    double* bn2Q   = (double*)(ws + 2560);
    float*  A1     = (float*)(ws + 4608);
    float*  AP     = (float*)(ws + 20992);
    float*  XT     = (float*)(ws + 37376);                 // [g][f][c] = 52428800 B
    float*  Y1     = XT;                                   // in-place; k3a also writes H2+rnk into slab fronts
    float*  Y2     = (float*)(ws + 37376 + 52428800);      // Nk*64 f32 = 23756800 B
    float*  out    = (float*)d_out;

    hipLaunchKernelGGL(k_trans, dim3(2049), dim3(256), 0, stream,
                       h, XT, ei, ew, A1, AP, bn1S, bn1Q, bn2S, bn2Q);
    hipLaunchKernelGGL(k1_gc1, dim3(Gc), dim3(256), 0, stream,
                       XT, W1, b1, A1, Y1, bn1S, bn1Q);
    hipLaunchKernelGGL(k3a_pool, dim3(Gc), dim3(256), 0, stream,
                       Y1, bn1S, bn1Q, g1, be1, a1, Wp, bp, AP, W2);
    hipLaunchKernelGGL(k3b_gc2, dim3(Gc), dim3(256), 0, stream,
                       Y1, ei, ew, b2, Y2, bn2S, bn2Q);
    hipLaunchKernelGGL(k5_out, dim3(Gc), dim3(256), 0, stream,
                       Y2, bn2S, bn2Q, g2, be2, a2, out);
}